// Round 2
// baseline (341.135 us; speedup 1.0000x reference)
//
#include <hip/hip_runtime.h>
#include <math.h>

#define B_ 2
#define N_ 16384
#define V_ 10475
#define J_ 55
#define K_ 6

constexpr int SEG  = 8;     // V-segments per point
constexpr int PTS  = 64;    // points per block
constexpr int TILE = 2048;  // verts staged in LDS per tile
constexpr int KBLK = SEG * PTS;  // 512 threads

// ---------------------------------------------------------------------------
// P0: pack verts as (x,y,z,v2) and points as (px,py,pz,p2) into ws (f32,
// screening only — final decisions are re-done in f64)
// ---------------------------------------------------------------------------
__global__ void prep_kernel(const float* __restrict__ x,
                            const float* __restrict__ cam,
                            const float* __restrict__ pverts,
                            float4* __restrict__ pv,
                            float4* __restrict__ px) {
    int i = blockIdx.x * blockDim.x + threadIdx.x;
    const int nv = B_ * V_;
    if (i < nv) {
        float vx = pverts[i * 3 + 0];
        float vy = pverts[i * 3 + 1];
        float vz = pverts[i * 3 + 2];
        float v2 = vx * vx + vy * vy + vz * vz;
        pv[i] = make_float4(vx, vy, vz, v2);
    }
    int j = i - nv;
    if (j >= 0 && j < B_ * N_) {
        int b = j >> 14;  // j / N_
        float s  = cam[b * 3 + 0];
        float tx = cam[b * 3 + 1];
        float ty = cam[b * 3 + 2];
        float X = x[j * 3 + 0], Y = x[j * 3 + 1], Z = x[j * 3 + 2];
        float pxv = X / s - tx;
        float pyv = Y / s - ty;
        float pzv = Z / s;
        float p2 = pxv * pxv + pyv * pyv + pzv * pzv;
        px[j] = make_float4(pxv, pyv, pzv, p2);
    }
}

// ---------------------------------------------------------------------------
// K1: f32 screen (top-6 per V-segment) + f64 re-rank of the 48-candidate pool
// block = 64 points x 8 segments (one wave per segment)
// ---------------------------------------------------------------------------
__global__ __launch_bounds__(KBLK) void knn_kernel(const float4* __restrict__ pv,
                                                   const float4* __restrict__ px,
                                                   const float* __restrict__ x,
                                                   const float* __restrict__ cam,
                                                   const float* __restrict__ pverts,
                                                   int* __restrict__ outI,
                                                   double* __restrict__ outD) {
    __shared__ float4 tile[TILE];
    __shared__ int cI[SEG][PTS][K_];

    const int tid = threadIdx.x;
    const int s = tid >> 6;   // segment 0..7
    const int p = tid & 63;   // point-in-block
    const int bid = blockIdx.x;
    const int b = bid >> 8;                 // 256 blocks per batch
    const int n = ((bid & 255) << 6) + p;

    const float4 P = px[b * N_ + n];

    float bD[K_];
    int   bI[K_];
#pragma unroll
    for (int k = 0; k < K_; ++k) { bD[k] = 3.4e38f; bI[k] = -1; }

    const float4* vb = pv + b * V_;
    for (int t0 = 0; t0 < V_; t0 += TILE) {
        const int cnt = min(TILE, V_ - t0);
        for (int i = tid; i < cnt; i += KBLK) tile[i] = vb[t0 + i];
        __syncthreads();

        const int lo = s * (TILE / SEG);
        const int hi = min(lo + (TILE / SEG), cnt);
        for (int i = lo; i < hi; ++i) {
            float4 q = tile[i];
            float dot = fmaf(P.z, q.z, fmaf(P.y, q.y, P.x * q.x));
            float d2  = fmaf(-2.0f, dot, P.w + q.w);
            if (d2 < bD[K_ - 1]) {
                bD[K_ - 1] = d2;
                bI[K_ - 1] = t0 + i;
#pragma unroll
                for (int k = K_ - 1; k > 0; --k) {
                    if (bD[k] < bD[k - 1]) {
                        float td = bD[k]; bD[k] = bD[k - 1]; bD[k - 1] = td;
                        int   ti = bI[k]; bI[k] = bI[k - 1]; bI[k - 1] = ti;
                    }
                }
            }
        }
        __syncthreads();
    }

#pragma unroll
    for (int k = 0; k < K_; ++k) cI[s][p][k] = bI[k];
    __syncthreads();

    if (s == 0) {
        // --- f64 re-rank of the 48-candidate pool, reference arithmetic ---
        const int gp = b * N_ + n;
        const double cs = (double)cam[b * 3 + 0];
        const double tx = (double)cam[b * 3 + 1];
        const double ty = (double)cam[b * 3 + 2];
        const double PX = (double)x[gp * 3 + 0] / cs - tx;
        const double PY = (double)x[gp * 3 + 1] / cs - ty;
        const double PZ = (double)x[gp * 3 + 2] / cs;
        const double P2 = PX * PX + PY * PY + PZ * PZ;

        double mD[K_];
        int    mI[K_];
#pragma unroll
        for (int k = 0; k < K_; ++k) { mD[k] = 1.0e300; mI[k] = 0x7fffffff; }

        for (int ss = 0; ss < SEG; ++ss) {
            for (int k = 0; k < K_; ++k) {
                int gi = cI[ss][p][k];
                if (gi < 0) continue;
                const float* vp = pverts + ((size_t)(b * V_ + gi)) * 3;
                double vx = (double)vp[0], vy = (double)vp[1], vz = (double)vp[2];
                double v2 = vx * vx + vy * vy + vz * vz;
                double dot = PX * vx + PY * vy + PZ * vz;
                double d = P2 + v2 - 2.0 * dot;   // reference expanded formula
                bool ins = (d < mD[K_ - 1]) ||
                           (d == mD[K_ - 1] && gi < mI[K_ - 1]);
                if (ins) {
                    mD[K_ - 1] = d; mI[K_ - 1] = gi;
#pragma unroll
                    for (int k2 = K_ - 1; k2 > 0; --k2) {
                        bool sw = (mD[k2] < mD[k2 - 1]) ||
                                  (mD[k2] == mD[k2 - 1] && mI[k2] < mI[k2 - 1]);
                        if (sw) {
                            double td = mD[k2]; mD[k2] = mD[k2 - 1]; mD[k2 - 1] = td;
                            int    ti = mI[k2]; mI[k2] = mI[k2 - 1]; mI[k2 - 1] = ti;
                        }
                    }
                }
            }
        }
        const int base = gp * K_;
#pragma unroll
        for (int k = 0; k < K_; ++k) { outI[base + k] = mI[k]; outD[base + k] = mD[k]; }
    }
}

// ---------------------------------------------------------------------------
// K2: conf + weights + transform blend + apply — all in f64 (O(N*K), cheap)
// ---------------------------------------------------------------------------
__global__ __launch_bounds__(256) void epilogue_kernel(const float* __restrict__ lbs,
                                                       const float* __restrict__ vt,
                                                       const float* __restrict__ x,
                                                       const float* __restrict__ cam,
                                                       const int* __restrict__ knnI,
                                                       const double* __restrict__ knnD,
                                                       float* __restrict__ out) {
    int i = blockIdx.x * blockDim.x + threadIdx.x;
    if (i >= B_ * N_) return;
    const int b = i >> 14;  // i / N_

    const double cs = (double)cam[b * 3 + 0];
    const double tx = (double)cam[b * 3 + 1];
    const double ty = (double)cam[b * 3 + 2];
    const double PX = (double)x[i * 3 + 0] / cs - tx;
    const double PY = (double)x[i * 3 + 1] / cs - ty;
    const double PZ = (double)x[i * 3 + 2] / cs;

    int idx[K_];
    double d2[K_];
#pragma unroll
    for (int k = 0; k < K_; ++k) { idx[k] = knnI[i * K_ + k]; d2[k] = knnD[i * K_ + k]; }

    // nearest-neighbor lbs row cached (f32 values are exact in f64)
    const float* row0 = lbs + idx[0] * J_;
    float r0[J_];
#pragma unroll
    for (int j = 0; j < J_; ++j) r0[j] = row0[j];

    const double WSTD2 = 2.0 * (0.1 * 0.1);   // python 0.020000000000000004

    double w[K_];
    w[0] = exp(-fmax(d2[0], 0.0));            // conf(k=0) == 1 always
#pragma unroll
    for (int k = 1; k < K_; ++k) {
        const float* rowk = lbs + idx[k] * J_;
        double ssum = 0.0;
        for (int j = 0; j < J_; ++j)
            ssum += fabs((double)rowk[j] - (double)r0[j]);
        double conf = (exp(-(ssum / WSTD2)) > 0.9) ? 1.0 : 0.0;
        w[k] = exp(-fmax(d2[k], 0.0)) * conf;
    }
    double wsum = 0.0;
#pragma unroll
    for (int k = 0; k < K_; ++k) wsum += w[k];

    double acc[12];
#pragma unroll
    for (int r = 0; r < 12; ++r) acc[r] = 0.0;
#pragma unroll
    for (int k = 0; k < K_; ++k) {
        double wk = w[k] / wsum;
        const float4* T = (const float4*)(vt + ((size_t)(b * V_ + idx[k])) * 16);
#pragma unroll
        for (int r = 0; r < 3; ++r) {
            float4 row = T[r];
            acc[r * 4 + 0] += wk * (double)row.x;
            acc[r * 4 + 1] += wk * (double)row.y;
            acc[r * 4 + 2] += wk * (double)row.z;
            acc[r * 4 + 3] += wk * (double)row.w;
        }
    }
    double ox = acc[0] * PX + acc[1] * PY + acc[2]  * PZ + acc[3];
    double oy = acc[4] * PX + acc[5] * PY + acc[6]  * PZ + acc[7];
    double oz = acc[8] * PX + acc[9] * PY + acc[10] * PZ + acc[11];
    out[i * 3 + 0] = (float)ox;
    out[i * 3 + 1] = (float)oy;
    out[i * 3 + 2] = (float)oz;
}

// ---------------------------------------------------------------------------
extern "C" void kernel_launch(void* const* d_in, const int* in_sizes, int n_in,
                              void* d_out, int out_size, void* d_ws, size_t ws_size,
                              hipStream_t stream) {
    const float* x      = (const float*)d_in[0];  // [B,N,3]
    const float* cam    = (const float*)d_in[1];  // [B,3]
    const float* lbs    = (const float*)d_in[2];  // [V,J]
    const float* vt     = (const float*)d_in[3];  // [B,V,4,4]
    const float* pverts = (const float*)d_in[4];  // [B,V,3]
    float* out = (float*)d_out;                   // [B,N,3]

    char* ws = (char*)d_ws;
    float4* pv   = (float4*)ws;                                       // B*V float4
    float4* px   = (float4*)(ws + (size_t)B_ * V_ * 16);              // B*N float4
    int*    knnI = (int*)(ws + (size_t)B_ * V_ * 16 + (size_t)B_ * N_ * 16);
    double* knnD = (double*)((char*)knnI + (size_t)B_ * N_ * K_ * 4); // 8B-aligned

    const int totalPrep = B_ * V_ + B_ * N_;
    prep_kernel<<<(totalPrep + 255) / 256, 256, 0, stream>>>(x, cam, pverts, pv, px);
    knn_kernel<<<B_ * (N_ / PTS), KBLK, 0, stream>>>(pv, px, x, cam, pverts, knnI, knnD);
    epilogue_kernel<<<(B_ * N_ + 255) / 256, 256, 0, stream>>>(lbs, vt, x, cam, knnI, knnD, out);
}